// Round 3
// baseline (746.041 us; speedup 1.0000x reference)
//
#include <hip/hip_runtime.h>

// SingleGcnLayer: y = relu( ((targets ⊕ Σ_k neighbors) @ kernel) / guard(Σ a) )
// targets[32,1024,256] f32, neighbors[32,1024,16,256] f32, a[32,1024,17] f32,
// kernel[256,256] f32 -> out[32,1024,256] f32.
//
// Round 3: ZERO LDS, ZERO barriers. K (256 KB) is L2-resident; each wave
// reads its K rows directly from L2 (b128, lane-contiguous). s and the
// degree factor live in registers and broadcast via v_readlane. Fully
// independent waves drift -> phase-2 VALU hides under the phase-1 HBM
// stream instead of serializing after it.

typedef float v4f __attribute__((ext_vector_type(4)));

#define BB 32
#define NN 1024
#define KK 16
#define DD 256
#define LL 256
#define ROWS 32      // rows (b,n) per block; 8 per wave
#define DTILE 8      // K rows fetched per inner pass (32 VGPRs)
#define NPASS (DD / DTILE)
#define NTHREADS 256

__device__ __forceinline__ float bcast(float x, int l) {
    return __int_as_float(__builtin_amdgcn_readlane(__float_as_int(x), l));
}

__global__ __launch_bounds__(NTHREADS, 4)   // cap VGPR<=128 -> 16 waves/CU
void gcn_fused(const float* __restrict__ targets,
               const float* __restrict__ neighbors,
               const float* __restrict__ a,
               const float* __restrict__ kern,
               float* __restrict__ out) {
    const int t        = threadIdx.x;
    const int w        = t >> 6;       // wave 0..3
    const int lane     = t & 63;
    const int row_base = blockIdx.x * ROWS;

    // ---- degree factor, registers only: lane l computes row w*8 + (l&7)
    // (lanes 8..63 redundant; same addresses -> L1 broadcast). Row r's value
    // ends up in lane r of this wave -> readlane in the epilogue.
    float fsum = 0.0f;
    {
        const float* ap = a + (size_t)(row_base + w * 8 + (lane & 7)) * (KK + 1);
        #pragma unroll
        for (int j = 0; j < KK + 1; ++j) fsum += ap[j];
    }
    const float invf = (fsum > 0.5f) ? (1.0f / fsum) : 1.0f;

    // ---- phase 1: sreg[r] = targets[row] + sum_k neighbors[row][k] ----
    // wave w owns rows w*8..w*8+7; lane holds d = 4*lane..4*lane+3.
    // 537 MB streamed once, nontemporal (keeps K in L2).
    const v4f* t4 = (const v4f*)targets;
    const v4f* n4 = (const v4f*)neighbors;
    v4f sreg[8];
    #pragma unroll
    for (int r = 0; r < 8; ++r) {
        const size_t grow = (size_t)(row_base + w * 8 + r);
        v4f accum = __builtin_nontemporal_load(&t4[grow * (DD / 4) + lane]);
        #pragma unroll 4
        for (int k = 0; k < KK; ++k) {
            accum += __builtin_nontemporal_load(
                &n4[(grow * KK + k) * (DD / 4) + lane]);
        }
        sreg[r] = accum;
    }

    v4f acc[8];
    #pragma unroll
    for (int r = 0; r < 8; ++r) acc[r] = v4f{0.0f, 0.0f, 0.0f, 0.0f};

    // ---- phase 2: acc[r][4*lane..+3] += s[r][d] * K[d][4*lane..+3] ----
    // K rows straight from L2; no LDS, no barriers. 8 independent loads per
    // pass give the VMEM pipe depth; 288 VALU insts per pass amortize L2 lat.
    const v4f* k4 = (const v4f*)kern;
    for (int dt = 0; dt < NPASS; ++dt) {
        v4f kv[DTILE];
        #pragma unroll
        for (int dd = 0; dd < DTILE; ++dd)
            kv[dd] = k4[(size_t)(dt * DTILE + dd) * (LL / 4) + lane];
        #pragma unroll
        for (int dd = 0; dd < DTILE; ++dd) {
            const int d     = dt * DTILE + dd;
            const int chunk = d >> 2;          // wave-uniform source lane
            #pragma unroll
            for (int r = 0; r < 8; ++r) {
                const float sv = bcast(sreg[r][d & 3], chunk);  // s[r][d] -> SGPR
                acc[r] += sv * kv[dd];                          // v_fmac w/ SGPR src
            }
        }
    }

    // ---- epilogue: normalize, relu, coalesced nontemporal store ----
    #pragma unroll
    for (int r = 0; r < 8; ++r) {
        const float inv = bcast(invf, r);      // lane r holds row w*8+r's factor
        v4f v = acc[r] * inv;
        v.x = fmaxf(v.x, 0.0f);
        v.y = fmaxf(v.y, 0.0f);
        v.z = fmaxf(v.z, 0.0f);
        v.w = fmaxf(v.w, 0.0f);
        __builtin_nontemporal_store(
            v, (v4f*)&out[(size_t)(row_base + w * 8 + r) * LL + 4 * lane]);
    }
}

extern "C" void kernel_launch(void* const* d_in, const int* in_sizes, int n_in,
                              void* d_out, int out_size, void* d_ws, size_t ws_size,
                              hipStream_t stream) {
    const float* targets   = (const float*)d_in[0];
    const float* neighbors = (const float*)d_in[1];
    const float* a         = (const float*)d_in[2];
    const float* kern      = (const float*)d_in[3];
    float* out = (float*)d_out;
    const int blocks = (BB * NN) / ROWS;   // 1024
    gcn_fused<<<dim3(blocks), dim3(NTHREADS), 0, stream>>>(targets, neighbors, a, kern, out);
}